// Round 15
// baseline (301.008 us; speedup 1.0000x reference)
//
#include <hip/hip_runtime.h>
#include <hip/hip_bf16.h>
#include <math.h>

#define BATCH  64
#define SEQ    2048
#define DMODEL 512
#define ATT    256
#define M_TOTAL (BATCH * SEQ)

#define MT     64                       // rows per block
#define KC     32                       // k per chunk
#define NCHUNK 16
#define BCH    (ATT * KC)               // 8192 ushorts = 16 KB per B chunk half
#define WA_LO_OFF (NCHUNK * BCH)        // 131072 ushorts

#define NBLK   (M_TOTAL / MT)           // 2048 fused blocks
#define BPB    (SEQ / MT)               // 32 blocks per batch row

// d_ws layout
#define PF_OFF  (1u << 20)                              // 4 MB: [2048][512] f32
#define ML_OFF  (PF_OFF + (size_t)NBLK * DMODEL * 4)    // 16 KB: [2048] float2
#define BS_OFF  (ML_OFF + (size_t)NBLK * 8)             // 512 B: [64] float2

typedef __attribute__((ext_vector_type(8))) short short8v;
typedef __attribute__((ext_vector_type(4))) float floatx4;

__device__ __forceinline__ ushort f2bf_rne(float f) {
    unsigned u = __float_as_uint(f);
    u += 0x7FFFu + ((u >> 16) & 1u);
    return (ushort)(u >> 16);
}
__device__ __forceinline__ float bf2f(ushort h) {
    return __uint_as_float(((unsigned)h) << 16);
}
__device__ __forceinline__ void gll16(const void* g, void* l) {
    __builtin_amdgcn_global_load_lds(
        (const __attribute__((address_space(1))) unsigned*)g,
        (__attribute__((address_space(3))) unsigned*)l, 16, 0, 0);
}
// sign-free fast tanh: 1 - 2/(e^{2x}+1); exact at +-inf, 0
__device__ __forceinline__ float fast_tanh(float x) {
    return 1.0f - 2.0f * __builtin_amdgcn_rcpf(__expf(x + x) + 1.0f);
}
// float4 -> packed bf16 hi (truncation) + lo (RNE of remainder)
__device__ __forceinline__ void cvt4(float4 v, uint2& hi, uint2& lo) {
    unsigned u0 = __float_as_uint(v.x), u1 = __float_as_uint(v.y);
    unsigned u2 = __float_as_uint(v.z), u3 = __float_as_uint(v.w);
    hi.x = __builtin_amdgcn_perm(u1, u0, 0x07060302u);   // [bf(y):bf(x)]
    hi.y = __builtin_amdgcn_perm(u3, u2, 0x07060302u);
    float r0 = v.x - __uint_as_float(u0 & 0xFFFF0000u);
    float r1 = v.y - __uint_as_float(u1 & 0xFFFF0000u);
    float r2 = v.z - __uint_as_float(u2 & 0xFFFF0000u);
    float r3 = v.w - __uint_as_float(u3 & 0xFFFF0000u);
    asm("v_cvt_pk_bf16_f32 %0, %1, %2" : "=v"(lo.x) : "v"(r0), "v"(r1));
    asm("v_cvt_pk_bf16_f32 %0, %1, %2" : "=v"(lo.y) : "v"(r2), "v"(r3));
}
// 8 floats -> hi/lo packed images (k-order preserved)
__device__ __forceinline__ void cvt8(float4 a, float4 b, uint4& hi, uint4& lo) {
    uint2 h0, l0, h1, l1;
    cvt4(a, h0, l0);
    cvt4(b, h1, l1);
    hi = make_uint4(h0.x, h0.y, h1.x, h1.y);
    lo = make_uint4(l0.x, l0.y, l1.x, l1.y);
}

// K0: Wa fp32 [256][512] -> bf16 hi/lo per-chunk quad-major images:
// elem (a, k): chunk kc=k>>5, quad q=(k&31)>>3 -> kc*8192 + (q*256+a)*8 + (k&7)
__global__ __launch_bounds__(256)
void wa_convert_kernel(const float* __restrict__ Wa, ushort* __restrict__ out) {
    int idx = blockIdx.x * 256 + threadIdx.x;   // 131072
    float x = Wa[idx];
    ushort hi = f2bf_rne(x);
    ushort lo = f2bf_rne(x - bf2f(hi));
    int a = idx >> 9, k = idx & 511;
    int kc = k >> 5, kk = k & 31, q = kk >> 3;
    size_t o = (size_t)kc * BCH + (size_t)(q * 256 + a) * 8 + (kk & 7);
    out[o] = hi;
    out[WA_LO_OFF + o] = lo;
}

// KF: fused scores GEMM + tanh-reduce + block softmax + partial GEVM.
// m97-occupancy structure: 512 thr / 8 waves; wave-tile 32x64 (wm=wid>>2,
// wn=wid&3): rows [wm*32,+32) x cols [wn*64,+64); acc = 32 regs. B single-
// buffered 32 KB (quad-major via gll); A per-lane regs, 1-chunk prefetch.
// ~33 KB LDS, <=85 regs -> 3 independent blocks/CU (24 waves) decorrelate
// the staging stalls that lockstep 2-block configs time-sliced.
__global__ __launch_bounds__(512, 6)
void fused_kernel(const float* __restrict__ X,
                  const ushort* __restrict__ wa_cvt,
                  const float* __restrict__ ba,
                  const float* __restrict__ ae,
                  float* __restrict__ zg,
                  float* __restrict__ pfeat,
                  float2* __restrict__ pml) {
    __shared__ __align__(16) ushort bbuf[2 * BCH];   // 32 KB: hi 16K | lo 16K
    __shared__ float zb[4][MT];
    __shared__ float pbuf[MT];

    const int tid = threadIdx.x;
    const int l   = tid & 63;
    const int wid = tid >> 6;
    const int wm  = wid >> 2, wn = wid & 3;
    const int n   = l & 15, g = l >> 4;
    const int m0  = blockIdx.x * MT;

    // B gll: waves 0-3 stage hi plane (16 KB), waves 4-7 lo; bumped pointer.
    const char* bsrc = (const char*)(wid < 4 ? wa_cvt : wa_cvt + WA_LO_OFF)
                       + (wid & 3) * 4096 + l * 16;
    char* const bdst = (char*)bbuf + wid * 4096;
    // A: lane rows = m0 + wm*32 + {0,16} + n, k-window g*8; bumped pointers.
    const float* ap0 = X + (size_t)(m0 + wm * 32 + n) * DMODEL + g * 8;
    const float* ap1 = ap0 + 16 * DMODEL;
    // B frag base (quad-major): (g*256 + col)*8 ushorts, col = wn*64 + nj*16 + n
    const int bb = (g * 256 + wn * 64 + n) * 8;

    floatx4 acc[2][4];
    #pragma unroll
    for (int i = 0; i < 2; ++i)
        #pragma unroll
        for (int j = 0; j < 4; ++j)
            acc[i][j] = (floatx4){0.f, 0.f, 0.f, 0.f};

    // ---- prologue: gll B(0); issue A(0); drain glls only ----
    #pragma unroll
    for (int i = 0; i < 4; ++i)
        gll16(bsrc + i * 1024, bdst + i * 1024);
    bsrc += 16384;
    asm volatile("" ::: "memory");       // glls precede A loads in VMEM order
    float4 xr0[2], xr1[2];
    xr0[0] = *(const float4*)(ap0);
    xr1[0] = *(const float4*)(ap0 + 4);
    xr0[1] = *(const float4*)(ap1);
    xr1[1] = *(const float4*)(ap1 + 4);
    ap0 += KC; ap1 += KC;
    asm volatile("s_waitcnt vmcnt(4)" ::: "memory");   // B(0) ready; A flying
    __builtin_amdgcn_s_barrier();

    #pragma unroll 1
    for (int kc = 0; kc < NCHUNK; ++kc) {
        const bool more = (kc + 1 < NCHUNK);
        const ushort* bh_t = bbuf;
        const ushort* bl_t = bbuf + BCH;

        // convert this chunk's A (loads arrived during previous chunk)
        short8v ah[2], av[2];
        cvt8(xr0[0], xr1[0], *(uint4*)&ah[0], *(uint4*)&av[0]);
        cvt8(xr0[1], xr1[1], *(uint4*)&ah[1], *(uint4*)&av[1]);

        // compute: 8 b128 B-frag reads + 24 MFMAs, prioritized
        __builtin_amdgcn_s_setprio(1);
        #pragma unroll
        for (int nj = 0; nj < 4; ++nj) {
            short8v bh = *(const short8v*)&bh_t[bb + nj * 128];
            short8v bv = *(const short8v*)&bl_t[bb + nj * 128];
            #pragma unroll
            for (int mi = 0; mi < 2; ++mi) {
                acc[mi][nj] = __builtin_amdgcn_mfma_f32_16x16x32_bf16(av[mi], bh, acc[mi][nj], 0, 0, 0);
                acc[mi][nj] = __builtin_amdgcn_mfma_f32_16x16x32_bf16(ah[mi], bv, acc[mi][nj], 0, 0, 0);
                acc[mi][nj] = __builtin_amdgcn_mfma_f32_16x16x32_bf16(ah[mi], bh, acc[mi][nj], 0, 0, 0);
            }
        }
        __builtin_amdgcn_s_setprio(0);

        if (more) {
            __builtin_amdgcn_s_barrier();          // all waves done reading buf
            #pragma unroll
            for (int i = 0; i < 4; ++i)
                gll16(bsrc + i * 1024, bdst + i * 1024);
            bsrc += 16384;
            asm volatile("" ::: "memory");         // glls before A in VMEM order
            xr0[0] = *(const float4*)(ap0);
            xr1[0] = *(const float4*)(ap0 + 4);
            xr0[1] = *(const float4*)(ap1);
            xr1[1] = *(const float4*)(ap1 + 4);
            ap0 += KC; ap1 += KC;
            asm volatile("s_waitcnt vmcnt(4)" ::: "memory");  // B ready; A flies
            __builtin_amdgcn_s_barrier();
        }
    }

    // ---- z epilogue: row = wm*32 + mi*16 + g*4 + e, col = wn*64 + nj*16 + n
    float bav[4], aev[4];
    #pragma unroll
    for (int nj = 0; nj < 4; ++nj) {
        int c = wn * 64 + nj * 16 + n;
        bav[nj] = ba[c];
        aev[nj] = ae[c];
    }
    #pragma unroll
    for (int mi = 0; mi < 2; ++mi) {
        float zp[4] = {0.f, 0.f, 0.f, 0.f};
        #pragma unroll
        for (int nj = 0; nj < 4; ++nj)
            #pragma unroll
            for (int e = 0; e < 4; ++e)
                zp[e] += fast_tanh(acc[mi][nj][e] + bav[nj]) * aev[nj];
        #pragma unroll
        for (int off = 8; off >= 1; off >>= 1)
            #pragma unroll
            for (int e = 0; e < 4; ++e)
                zp[e] += __shfl_xor(zp[e], off, 64);
        if (n == 0)
            *(float4*)&zb[wn][wm * 32 + mi * 16 + g * 4] =
                make_float4(zp[0], zp[1], zp[2], zp[3]);
    }
    __syncthreads();

    // ---- block softmax partials over 64 rows (single wave; no LDS reduce)
    if (tid < MT) {
        float zsum = (zb[0][tid] + zb[1][tid]) + (zb[2][tid] + zb[3][tid]);
        zg[m0 + tid] = zsum;
        float m = zsum;
        #pragma unroll
        for (int off = 32; off >= 1; off >>= 1)
            m = fmaxf(m, __shfl_xor(m, off, 64));
        float p = __expf(zsum - m);
        pbuf[tid] = p;
        float s = p;
        #pragma unroll
        for (int off = 32; off >= 1; off >>= 1)
            s += __shfl_xor(s, off, 64);
        if (tid == 0) pml[blockIdx.x] = make_float2(m, s);
    }
    __syncthreads();

    // ---- partial feature GEVM: pfeat[blk][f] = sum_s p[s]*X[m0+s][f] (L2-hot)
    {
        float a0 = 0.f, a1 = 0.f, a2 = 0.f, a3 = 0.f;
        const float* xc = X + (size_t)m0 * DMODEL + tid;
        #pragma unroll 4
        for (int s = 0; s < MT; s += 4) {
            a0 = fmaf(xc[(size_t)(s + 0) * DMODEL], pbuf[s + 0], a0);
            a1 = fmaf(xc[(size_t)(s + 1) * DMODEL], pbuf[s + 1], a1);
            a2 = fmaf(xc[(size_t)(s + 2) * DMODEL], pbuf[s + 2], a2);
            a3 = fmaf(xc[(size_t)(s + 3) * DMODEL], pbuf[s + 3], a3);
        }
        pfeat[(size_t)blockIdx.x * DMODEL + tid] = (a0 + a1) + (a2 + a3);
    }
}

// K-combine: per batch, merge 32 block partials with online-softmax rescale.
__global__ __launch_bounds__(512)
void combine_kernel(const float* __restrict__ pfeat, const float2* __restrict__ pml,
                    float* __restrict__ feat, float2* __restrict__ bstat) {
    const int b = blockIdx.x, tid = threadIdx.x;
    float M = -3.0e38f;
    #pragma unroll
    for (int c = 0; c < BPB; ++c)
        M = fmaxf(M, pml[b * BPB + c].x);
    float L = 0.f, s = 0.f;
    #pragma unroll 4
    for (int c = 0; c < BPB; ++c) {
        float2 ml = pml[b * BPB + c];
        float sc = __expf(ml.x - M);
        L += sc * ml.y;
        s = fmaf(sc, pfeat[(size_t)(b * BPB + c) * DMODEL + tid], s);
    }
    feat[(size_t)b * DMODEL + tid] = s / L;
    if (tid == 0) bstat[b] = make_float2(M, L);
}

// K-weights: w[b,s] = exp(z - M_b) / L_b, in place over zg.
__global__ __launch_bounds__(256)
void weights_kernel(float* __restrict__ zw, const float2* __restrict__ bstat) {
    int i = blockIdx.x * 256 + threadIdx.x;   // 131072
    float2 ml = bstat[i >> 11];               // SEQ = 2048
    zw[i] = __expf(zw[i] - ml.x) / ml.y;
}

extern "C" void kernel_launch(void* const* d_in, const int* in_sizes, int n_in,
                              void* d_out, int out_size, void* d_ws, size_t ws_size,
                              hipStream_t stream) {
    const float* X  = (const float*)d_in[0];
    const float* Wa = (const float*)d_in[1];
    const float* ba = (const float*)d_in[2];
    const float* ae = (const float*)d_in[3];
    float* out  = (float*)d_out;
    float* feat = out;                       // [64][512]
    float* wgt  = out + BATCH * DMODEL;      // [64][2048]; holds z then weights

    ushort* wa_cvt  = (ushort*)d_ws;                          // 512 KB
    float*  pfeat   = (float*)((char*)d_ws + PF_OFF);         // 4 MB
    float2* pml     = (float2*)((char*)d_ws + ML_OFF);        // 16 KB
    float2* bstat   = (float2*)((char*)d_ws + BS_OFF);        // 512 B

    wa_convert_kernel<<<ATT * DMODEL / 256, 256, 0, stream>>>(Wa, wa_cvt);
    fused_kernel<<<NBLK, 512, 0, stream>>>(X, wa_cvt, ba, ae, wgt, pfeat, pml);
    combine_kernel<<<BATCH, 512, 0, stream>>>(pfeat, pml, feat, bstat);
    weights_kernel<<<M_TOTAL / 256, 256, 0, stream>>>(wgt, bstat);
}

// Round 16
// 139.950 us; speedup vs baseline: 2.1508x; 2.1508x over previous
//
#include <hip/hip_runtime.h>
#include <hip/hip_bf16.h>
#include <math.h>

#define BATCH  64
#define SEQ    2048
#define DMODEL 512
#define ATT    256
#define M_TOTAL (BATCH * SEQ)

#define MT     64                       // rows per block
#define KC     32                       // k per chunk
#define NCHUNK 16
#define BCH    (ATT * KC)               // 8192 ushorts = 16 KB per B chunk half
#define WA_LO_OFF (NCHUNK * BCH)        // 131072 ushorts

#define NBLK   (M_TOTAL / MT)           // 2048 fused blocks
#define BPB    (SEQ / MT)               // 32 blocks per batch row

// d_ws layout
#define PF_OFF  (1u << 20)                              // 4 MB: [2048][512] f32
#define ML_OFF  (PF_OFF + (size_t)NBLK * DMODEL * 4)    // 16 KB: [2048] float2
#define BS_OFF  (ML_OFF + (size_t)NBLK * 8)             // 512 B: [64] float2

typedef __attribute__((ext_vector_type(8))) short short8v;
typedef __attribute__((ext_vector_type(4))) float floatx4;

__device__ __forceinline__ ushort f2bf_rne(float f) {
    unsigned u = __float_as_uint(f);
    u += 0x7FFFu + ((u >> 16) & 1u);
    return (ushort)(u >> 16);
}
__device__ __forceinline__ float bf2f(ushort h) {
    return __uint_as_float(((unsigned)h) << 16);
}
__device__ __forceinline__ void gll16(const void* g, void* l) {
    __builtin_amdgcn_global_load_lds(
        (const __attribute__((address_space(1))) unsigned*)g,
        (__attribute__((address_space(3))) unsigned*)l, 16, 0, 0);
}
// sign-free fast tanh: 1 - 2/(e^{2x}+1); exact at +-inf, 0
__device__ __forceinline__ float fast_tanh(float x) {
    return 1.0f - 2.0f * __builtin_amdgcn_rcpf(__expf(x + x) + 1.0f);
}
// float4 -> packed bf16 hi (truncation) + lo (RNE of remainder)
__device__ __forceinline__ void cvt4(float4 v, uint2& hi, uint2& lo) {
    unsigned u0 = __float_as_uint(v.x), u1 = __float_as_uint(v.y);
    unsigned u2 = __float_as_uint(v.z), u3 = __float_as_uint(v.w);
    hi.x = __builtin_amdgcn_perm(u1, u0, 0x07060302u);   // [bf(y):bf(x)]
    hi.y = __builtin_amdgcn_perm(u3, u2, 0x07060302u);
    float r0 = v.x - __uint_as_float(u0 & 0xFFFF0000u);
    float r1 = v.y - __uint_as_float(u1 & 0xFFFF0000u);
    float r2 = v.z - __uint_as_float(u2 & 0xFFFF0000u);
    float r3 = v.w - __uint_as_float(u3 & 0xFFFF0000u);
    asm("v_cvt_pk_bf16_f32 %0, %1, %2" : "=v"(lo.x) : "v"(r0), "v"(r1));
    asm("v_cvt_pk_bf16_f32 %0, %1, %2" : "=v"(lo.y) : "v"(r2), "v"(r3));
}
// 8 floats -> hi/lo packed images (k-order preserved)
__device__ __forceinline__ void cvt8(float4 a, float4 b, uint4& hi, uint4& lo) {
    uint2 h0, l0, h1, l1;
    cvt4(a, h0, l0);
    cvt4(b, h1, l1);
    hi = make_uint4(h0.x, h0.y, h1.x, h1.y);
    lo = make_uint4(l0.x, l0.y, l1.x, l1.y);
}

// K0: Wa fp32 [256][512] -> bf16 hi/lo per-chunk quad-major images:
// elem (a, k): chunk kc=k>>5, quad q=(k&31)>>3 -> kc*8192 + (q*256+a)*8 + (k&7)
__global__ __launch_bounds__(256)
void wa_convert_kernel(const float* __restrict__ Wa, ushort* __restrict__ out) {
    int idx = blockIdx.x * 256 + threadIdx.x;   // 131072
    float x = Wa[idx];
    ushort hi = f2bf_rne(x);
    ushort lo = f2bf_rne(x - bf2f(hi));
    int a = idx >> 9, k = idx & 511;
    int kc = k >> 5, kk = k & 31, q = kk >> 3;
    size_t o = (size_t)kc * BCH + (size_t)(q * 256 + a) * 8 + (kk & 7);
    out[o] = hi;
    out[WA_LO_OFF + o] = lo;
}

// KF: fused scores GEMM + tanh-reduce + block softmax + partial GEVM.
// 256 thr / 4 waves; tile 64x256; wave (wm=wid>>1, wn=wid&1) owns rows
// [wm*32,+32) x cols [wn*128,+128) — R13's proven 128-reg wave code.
// B single-buffered 32 KB via gll; A per-lane regs, issued 1 chunk early.
// ~33.6 KB LDS, <=128 unified regs -> 4 INDEPENDENT blocks/CU: each SIMD
// hosts 4 waves from 4 different barrier groups (kills the 2x8 convoy).
__global__ __launch_bounds__(256, 4)
void fused_kernel(const float* __restrict__ X,
                  const ushort* __restrict__ wa_cvt,
                  const float* __restrict__ ba,
                  const float* __restrict__ ae,
                  float* __restrict__ zg,
                  float* __restrict__ pfeat,
                  float2* __restrict__ pml) {
    __shared__ __align__(16) ushort bbuf[2 * BCH];   // 32 KB: hi 16K | lo 16K
    __shared__ float zb[2][MT];
    __shared__ float pbuf[MT];

    const int tid = threadIdx.x;
    const int l   = tid & 63;
    const int wid = tid >> 6;
    const int wm  = wid >> 1, wn = wid & 1;
    const int n   = l & 15, g = l >> 4;
    const int m0  = blockIdx.x * MT;

    // B gll: waves 0-1 stage hi plane (segs 0-15), waves 2-3 lo; 8 glls/thr.
    const char* bsrc = (const char*)(wid < 2 ? wa_cvt : wa_cvt + WA_LO_OFF)
                       + (wid & 1) * 8192 + l * 16;
    char* const bdst = (char*)bbuf + wid * 8192;
    // A: lane rows = m0 + wm*32 + {0,16} + n, k-window g*8; bumped pointers.
    const float* ap0 = X + (size_t)(m0 + wm * 32 + n) * DMODEL + g * 8;
    const float* ap1 = ap0 + 16 * DMODEL;
    // B frag base (quad-major): (g*256 + col)*8 ushorts, col = wn*128 + nj*16 + n
    const int bb = (g * 256 + wn * 128 + n) * 8;

    floatx4 acc[2][8];
    #pragma unroll
    for (int i = 0; i < 2; ++i)
        #pragma unroll
        for (int j = 0; j < 8; ++j)
            acc[i][j] = (floatx4){0.f, 0.f, 0.f, 0.f};

    // ---- prologue: gll B(0); issue A(0); drain glls (A flies) ----
    #pragma unroll
    for (int i = 0; i < 8; ++i)
        gll16(bsrc + i * 1024, bdst + i * 1024);
    bsrc += 16384;
    asm volatile("" ::: "memory");       // glls precede A loads in VMEM order
    float4 xr0[2], xr1[2];
    xr0[0] = *(const float4*)(ap0);
    xr1[0] = *(const float4*)(ap0 + 4);
    xr0[1] = *(const float4*)(ap1);
    xr1[1] = *(const float4*)(ap1 + 4);
    ap0 += KC; ap1 += KC;
    asm volatile("s_waitcnt vmcnt(4)" ::: "memory");   // B(0) ready; A flying
    __builtin_amdgcn_s_barrier();

    #pragma unroll 1
    for (int kc = 0; kc < NCHUNK; ++kc) {
        const bool more = (kc + 1 < NCHUNK);
        const ushort* bh_t = bbuf;
        const ushort* bl_t = bbuf + BCH;

        // convert this chunk's A (loads arrived during previous chunk)
        short8v ah[2], av[2];
        cvt8(xr0[0], xr1[0], *(uint4*)&ah[0], *(uint4*)&av[0]);
        cvt8(xr0[1], xr1[1], *(uint4*)&ah[1], *(uint4*)&av[1]);

        // issue next-chunk A immediately (regs free post-cvt; a full chunk
        // of MFMA + staging covers the HBM latency)
        if (more) {
            xr0[0] = *(const float4*)(ap0);
            xr1[0] = *(const float4*)(ap0 + 4);
            xr0[1] = *(const float4*)(ap1);
            xr1[1] = *(const float4*)(ap1 + 4);
            ap0 += KC; ap1 += KC;
        }

        // compute: 16 b128 B-frag reads + 48 MFMAs, prioritized
        __builtin_amdgcn_s_setprio(1);
        #pragma unroll
        for (int nj = 0; nj < 8; ++nj) {
            short8v bh = *(const short8v*)&bh_t[bb + nj * 128];
            short8v bv = *(const short8v*)&bl_t[bb + nj * 128];
            #pragma unroll
            for (int mi = 0; mi < 2; ++mi) {
                acc[mi][nj] = __builtin_amdgcn_mfma_f32_16x16x32_bf16(av[mi], bh, acc[mi][nj], 0, 0, 0);
                acc[mi][nj] = __builtin_amdgcn_mfma_f32_16x16x32_bf16(ah[mi], bv, acc[mi][nj], 0, 0, 0);
                acc[mi][nj] = __builtin_amdgcn_mfma_f32_16x16x32_bf16(ah[mi], bh, acc[mi][nj], 0, 0, 0);
            }
        }
        __builtin_amdgcn_s_setprio(0);

        if (more) {
            __builtin_amdgcn_s_barrier();          // all waves done reading buf
            #pragma unroll
            for (int i = 0; i < 8; ++i)
                gll16(bsrc + i * 1024, bdst + i * 1024);
            bsrc += 16384;
            // A (issued long ago) is done; this drains just the fresh glls
            asm volatile("s_waitcnt vmcnt(0)" ::: "memory");
            __builtin_amdgcn_s_barrier();
        }
    }

    // ---- z epilogue: row = wm*32 + mi*16 + g*4 + e, col = wn*128 + nj*16 + n
    float bav[8], aev[8];
    #pragma unroll
    for (int nj = 0; nj < 8; ++nj) {
        int c = wn * 128 + nj * 16 + n;
        bav[nj] = ba[c];
        aev[nj] = ae[c];
    }
    #pragma unroll
    for (int mi = 0; mi < 2; ++mi) {
        float zp[4] = {0.f, 0.f, 0.f, 0.f};
        #pragma unroll
        for (int nj = 0; nj < 8; ++nj)
            #pragma unroll
            for (int e = 0; e < 4; ++e)
                zp[e] += fast_tanh(acc[mi][nj][e] + bav[nj]) * aev[nj];
        #pragma unroll
        for (int off = 8; off >= 1; off >>= 1)
            #pragma unroll
            for (int e = 0; e < 4; ++e)
                zp[e] += __shfl_xor(zp[e], off, 64);
        if (n == 0)
            *(float4*)&zb[wn][wm * 32 + mi * 16 + g * 4] =
                make_float4(zp[0], zp[1], zp[2], zp[3]);
    }
    __syncthreads();

    // ---- block softmax partials over 64 rows (single wave)
    if (tid < MT) {
        float zsum = zb[0][tid] + zb[1][tid];
        zg[m0 + tid] = zsum;
        float m = zsum;
        #pragma unroll
        for (int off = 32; off >= 1; off >>= 1)
            m = fmaxf(m, __shfl_xor(m, off, 64));
        float p = __expf(zsum - m);
        pbuf[tid] = p;
        float s = p;
        #pragma unroll
        for (int off = 32; off >= 1; off >>= 1)
            s += __shfl_xor(s, off, 64);
        if (tid == 0) pml[blockIdx.x] = make_float2(m, s);
    }
    __syncthreads();

    // ---- partial feature GEVM: pfeat[blk][f] = sum_s p[s]*X[m0+s][f] (L2-hot)
    {
        float a0 = 0.f, a1 = 0.f;
        const float* xc = X + (size_t)m0 * DMODEL + tid;
        #pragma unroll 4
        for (int s = 0; s < MT; ++s) {
            float ps = pbuf[s];
            a0 = fmaf(xc[(size_t)s * DMODEL], ps, a0);
            a1 = fmaf(xc[(size_t)s * DMODEL + 256], ps, a1);
        }
        pfeat[(size_t)blockIdx.x * DMODEL + tid]       = a0;
        pfeat[(size_t)blockIdx.x * DMODEL + tid + 256] = a1;
    }
}

// K-combine: per batch, merge 32 block partials with online-softmax rescale.
__global__ __launch_bounds__(512)
void combine_kernel(const float* __restrict__ pfeat, const float2* __restrict__ pml,
                    float* __restrict__ feat, float2* __restrict__ bstat) {
    const int b = blockIdx.x, tid = threadIdx.x;
    float M = -3.0e38f;
    #pragma unroll
    for (int c = 0; c < BPB; ++c)
        M = fmaxf(M, pml[b * BPB + c].x);
    float L = 0.f, s = 0.f;
    #pragma unroll 4
    for (int c = 0; c < BPB; ++c) {
        float2 ml = pml[b * BPB + c];
        float sc = __expf(ml.x - M);
        L += sc * ml.y;
        s = fmaf(sc, pfeat[(size_t)(b * BPB + c) * DMODEL + tid], s);
    }
    feat[(size_t)b * DMODEL + tid] = s / L;
    if (tid == 0) bstat[b] = make_float2(M, L);
}

// K-weights: w[b,s] = exp(z - M_b) / L_b, in place over zg.
__global__ __launch_bounds__(256)
void weights_kernel(float* __restrict__ zw, const float2* __restrict__ bstat) {
    int i = blockIdx.x * 256 + threadIdx.x;   // 131072
    float2 ml = bstat[i >> 11];               // SEQ = 2048
    zw[i] = __expf(zw[i] - ml.x) / ml.y;
}

extern "C" void kernel_launch(void* const* d_in, const int* in_sizes, int n_in,
                              void* d_out, int out_size, void* d_ws, size_t ws_size,
                              hipStream_t stream) {
    const float* X  = (const float*)d_in[0];
    const float* Wa = (const float*)d_in[1];
    const float* ba = (const float*)d_in[2];
    const float* ae = (const float*)d_in[3];
    float* out  = (float*)d_out;
    float* feat = out;                       // [64][512]
    float* wgt  = out + BATCH * DMODEL;      // [64][2048]; holds z then weights

    ushort* wa_cvt  = (ushort*)d_ws;                          // 512 KB
    float*  pfeat   = (float*)((char*)d_ws + PF_OFF);         // 4 MB
    float2* pml     = (float2*)((char*)d_ws + ML_OFF);        // 16 KB
    float2* bstat   = (float2*)((char*)d_ws + BS_OFF);        // 512 B

    wa_convert_kernel<<<ATT * DMODEL / 256, 256, 0, stream>>>(Wa, wa_cvt);
    fused_kernel<<<NBLK, 256, 0, stream>>>(X, wa_cvt, ba, ae, wgt, pfeat, pml);
    combine_kernel<<<BATCH, 512, 0, stream>>>(pfeat, pml, feat, bstat);
    weights_kernel<<<M_TOTAL / 256, 256, 0, stream>>>(wgt, bstat);
}